// Round 1
// baseline (1769.332 us; speedup 1.0000x reference)
//
#include <hip/hip_runtime.h>
#include <math.h>

#define NLAYER 2
#define DMODEL 256
#define DINNER 512
#define DSTATE 16
#define DTRANK 16
#define DCONV  4
#define BB     4
#define LL     2048
#define BL     (BB*LL)

__device__ __forceinline__ float sigmoidf_(float x) { return 1.0f / (1.0f + __expf(-x)); }

// ---------------- embedding gather ----------------
__global__ void k_embed(const int* __restrict__ ids, const float* __restrict__ emb,
                        float* __restrict__ x) {
    int bl = blockIdx.x;
    int d  = threadIdx.x;
    int id = ids[bl];
    x[(size_t)bl * DMODEL + d] = emb[(size_t)id * DMODEL + d];
}

// ---------------- fp32 tiled GEMM: C[M,N] = A[M,K] @ B[K,N] ----------------
// 64x64 tile, BK=16, 256 threads, 4x4 per thread. M%64==0, N%64==0, K%16==0.
__global__ __launch_bounds__(256) void k_sgemm(const float* __restrict__ A,
                                               const float* __restrict__ B,
                                               float* __restrict__ C,
                                               int M, int N, int K) {
    const int tid = threadIdx.x;
    const int tx = tid & 15, ty = tid >> 4;
    const int m0 = blockIdx.y * 64, n0 = blockIdx.x * 64;
    __shared__ float As[16][64];
    __shared__ float Bs[16][64];
    float acc[4][4] = {};
    const int ar = tid >> 2;        // 0..63: row in A tile
    const int ak = (tid & 3) * 4;   // k offset
    const int bk = tid >> 4;        // 0..15: k row in B tile
    const int bn = (tid & 15) * 4;  // n offset
    for (int kk = 0; kk < K; kk += 16) {
        float4 av = *(const float4*)&A[(size_t)(m0 + ar) * K + kk + ak];
        float4 bv = *(const float4*)&B[(size_t)(kk + bk) * N + n0 + bn];
        As[ak + 0][ar] = av.x; As[ak + 1][ar] = av.y;
        As[ak + 2][ar] = av.z; As[ak + 3][ar] = av.w;
        *(float4*)&Bs[bk][bn] = bv;
        __syncthreads();
#pragma unroll
        for (int k = 0; k < 16; ++k) {
            float4 a = *(const float4*)&As[k][ty * 4];
            float4 b = *(const float4*)&Bs[k][tx * 4];
            float a4[4] = {a.x, a.y, a.z, a.w};
            float b4[4] = {b.x, b.y, b.z, b.w};
#pragma unroll
            for (int i = 0; i < 4; ++i)
#pragma unroll
                for (int j = 0; j < 4; ++j) acc[i][j] += a4[i] * b4[j];
        }
        __syncthreads();
    }
#pragma unroll
    for (int i = 0; i < 4; ++i) {
        float4 o = make_float4(acc[i][0], acc[i][1], acc[i][2], acc[i][3]);
        *(float4*)&C[(size_t)(m0 + ty * 4 + i) * N + n0 + tx * 4] = o;
    }
}

// ---------------- depthwise causal conv (D_CONV=4) + bias + SiLU ----------------
// u_raw lives in xz[:, 0:512]; writes u[BL,512]
__global__ void k_conv_silu(const float* __restrict__ xz, const float* __restrict__ cw,
                            const float* __restrict__ cb, float* __restrict__ u) {
    int idx = blockIdx.x * blockDim.x + threadIdx.x;  // over BL*DINNER
    int c  = idx & (DINNER - 1);
    int bl = idx >> 9;
    int l  = bl & (LL - 1);
    float acc = cb[c];
#pragma unroll
    for (int k = 0; k < DCONV; ++k) {
        int t = l - (DCONV - 1) + k;
        if (t >= 0) acc += cw[c * DCONV + k] * xz[(size_t)(bl - (DCONV - 1) + k) * 2 * DINNER + c];
    }
    u[(size_t)idx] = acc * sigmoidf_(acc);
}

// ---------------- fused x_proj (48 cols) + delta = softplus(dt@Wdt + b) ----------------
// one block per token
__global__ __launch_bounds__(256) void k_xproj_delta(const float* __restrict__ u,
                                                     const float* __restrict__ w_xp,
                                                     const float* __restrict__ w_dt,
                                                     const float* __restrict__ b_dt,
                                                     float* __restrict__ Bm,
                                                     float* __restrict__ Cm,
                                                     float* __restrict__ delta) {
    int bl = blockIdx.x;
    __shared__ float us[DINNER];
    __shared__ float dts[DTRANK];
    int tid = threadIdx.x;
    *(float2*)&us[tid * 2] = *(const float2*)&u[(size_t)bl * DINNER + tid * 2];
    __syncthreads();
    if (tid < 48) {
        float s = 0.f;
#pragma unroll 8
        for (int k = 0; k < DINNER; ++k) s += us[k] * w_xp[k * 48 + tid];
        if (tid < 16)      dts[tid] = s;
        else if (tid < 32) Bm[(size_t)bl * DSTATE + tid - 16] = s;
        else               Cm[(size_t)bl * DSTATE + tid - 32] = s;
    }
    __syncthreads();
#pragma unroll
    for (int cc = 0; cc < 2; ++cc) {
        int c = tid + cc * 256;
        float s = b_dt[c];
#pragma unroll
        for (int r = 0; r < DTRANK; ++r) s += dts[r] * w_dt[r * DINNER + c];
        delta[(size_t)bl * DINNER + c] = (s > 20.f) ? s : log1pf(__expf(s));
    }
}

// ---------------- selective scan, fused +u*D and *silu(res) ----------------
// block = 256 threads = 16 channels x 16 state lanes; grid = B * (DINNER/16)
__global__ __launch_bounds__(256) void k_scan(const float* __restrict__ delta,
                                              const float* __restrict__ u,
                                              const float* __restrict__ xz,
                                              const float* __restrict__ Bm,
                                              const float* __restrict__ Cm,
                                              const float* __restrict__ A_log,
                                              const float* __restrict__ Dp,
                                              float* __restrict__ y) {
    int tid = threadIdx.x;
    int n  = tid & 15;
    int cg = tid >> 4;                      // 0..15
    int b  = blockIdx.x >> 5;               // 32 blocks per batch (512/16)
    int c  = (blockIdx.x & 31) * 16 + cg;
    const float Ac = -__expf(A_log[c * DSTATE + n]);
    const float Dc = Dp[c];
    const int bl0 = b * LL;
    float dlt = delta[(size_t)bl0 * DINNER + c];
    float uu  = u[(size_t)bl0 * DINNER + c];
    float rr  = xz[(size_t)bl0 * 2 * DINNER + DINNER + c];
    float Bn  = Bm[(size_t)bl0 * DSTATE + n];
    float Cn  = Cm[(size_t)bl0 * DSTATE + n];
    float h = 0.f;
    for (int t = 0; t < LL; ++t) {
        // prefetch t+1 (independent of recurrence -> hides L2 latency)
        float dlt2 = 0.f, uu2 = 0.f, rr2 = 0.f, Bn2 = 0.f, Cn2 = 0.f;
        if (t + 1 < LL) {
            int bl2 = bl0 + t + 1;
            dlt2 = delta[(size_t)bl2 * DINNER + c];
            uu2  = u[(size_t)bl2 * DINNER + c];
            rr2  = xz[(size_t)bl2 * 2 * DINNER + DINNER + c];
            Bn2  = Bm[(size_t)bl2 * DSTATE + n];
            Cn2  = Cm[(size_t)bl2 * DSTATE + n];
        }
        float dA = __expf(dlt * Ac);
        h = dA * h + (dlt * uu) * Bn;
        float p = h * Cn;
        p += __shfl_xor(p, 1, 16);
        p += __shfl_xor(p, 2, 16);
        p += __shfl_xor(p, 4, 16);
        p += __shfl_xor(p, 8, 16);
        if (n == 0) {
            float yv = p + uu * Dc;
            y[(size_t)(bl0 + t) * DINNER + c] = yv * (rr * sigmoidf_(rr));
        }
        dlt = dlt2; uu = uu2; rr = rr2; Bn = Bn2; Cn = Cn2;
    }
}

extern "C" void kernel_launch(void* const* d_in, const int* in_sizes, int n_in,
                              void* d_out, int out_size, void* d_ws, size_t ws_size,
                              hipStream_t stream) {
    const int*   ids   = (const int*)d_in[0];
    const float* emb   = (const float*)d_in[1];
    const float* w_in  = (const float*)d_in[2];
    const float* cw    = (const float*)d_in[3];
    const float* cb    = (const float*)d_in[4];
    const float* w_xp  = (const float*)d_in[5];
    const float* w_dt  = (const float*)d_in[6];
    const float* b_dt  = (const float*)d_in[7];
    const float* A_log = (const float*)d_in[8];
    const float* Dp    = (const float*)d_in[9];
    const float* w_out = (const float*)d_in[10];
    float* out = (float*)d_out;

    float* ws = (float*)d_ws;
    float* x   = ws;                              // BL*256
    float* xz  = x  + (size_t)BL * DMODEL;        // BL*1024
    float* u   = xz + (size_t)BL * 2 * DINNER;    // BL*512
    float* Bm  = u  + (size_t)BL * DINNER;        // BL*16
    float* Cm  = Bm + (size_t)BL * DSTATE;        // BL*16
    float* dlt = Cm + (size_t)BL * DSTATE;        // BL*512
    float* y   = dlt + (size_t)BL * DINNER;       // BL*512
    // total ~23.3M floats = 93.3 MB of d_ws

    k_embed<<<BL, DMODEL, 0, stream>>>(ids, emb, x);

    for (int l = 0; l < NLAYER; ++l) {
        dim3 g1(2 * DINNER / 64, BL / 64);
        k_sgemm<<<g1, 256, 0, stream>>>(x, w_in + (size_t)l * DMODEL * 2 * DINNER, xz,
                                        BL, 2 * DINNER, DMODEL);
        k_conv_silu<<<(BL * DINNER) / 256, 256, 0, stream>>>(
            xz, cw + l * DINNER * DCONV, cb + l * DINNER, u);
        k_xproj_delta<<<BL, 256, 0, stream>>>(u, w_xp + (size_t)l * DINNER * 48,
                                              w_dt + (size_t)l * DTRANK * DINNER,
                                              b_dt + (size_t)l * DINNER, Bm, Cm, dlt);
        k_scan<<<BB * DINNER / 16, 256, 0, stream>>>(dlt, u, xz, Bm, Cm,
                                                     A_log + (size_t)l * DINNER * DSTATE,
                                                     Dp + (size_t)l * DINNER, y);
        float* dst = (l == NLAYER - 1) ? out : x;
        dim3 g2(DMODEL / 64, BL / 64);
        k_sgemm<<<g2, 256, 0, stream>>>(y, w_out + (size_t)l * DINNER * DMODEL, dst,
                                        BL, DMODEL, DINNER);
    }
}

// Round 2
// 634.820 us; speedup vs baseline: 2.7871x; 2.7871x over previous
//
#include <hip/hip_runtime.h>
#include <math.h>

#define NLAYER 2
#define DMODEL 256
#define DINNER 512
#define DSTATE 16
#define DTRANK 16
#define DCONV  4
#define BB     4
#define LL     2048
#define BL     (BB*LL)
#define NCHUNK 16
#define LC     (LL/NCHUNK)   // 128
#define NREC   (BB*DINNER*DSTATE)  // 32768

__device__ __forceinline__ float sigmoidf_(float x) { return 1.0f / (1.0f + __expf(-x)); }

// ---------------- embedding gather ----------------
__global__ void k_embed(const int* __restrict__ ids, const float* __restrict__ emb,
                        float* __restrict__ x) {
    int bl = blockIdx.x;
    int d  = threadIdx.x;
    int id = ids[bl];
    x[(size_t)bl * DMODEL + d] = emb[(size_t)id * DMODEL + d];
}

// ---------------- fp32 tiled GEMM: C[M,N] = A[M,K] @ B[K,N] ----------------
__global__ __launch_bounds__(256) void k_sgemm(const float* __restrict__ A,
                                               const float* __restrict__ B,
                                               float* __restrict__ C,
                                               int M, int N, int K) {
    const int tid = threadIdx.x;
    const int tx = tid & 15, ty = tid >> 4;
    const int m0 = blockIdx.y * 64, n0 = blockIdx.x * 64;
    __shared__ float As[16][64];
    __shared__ float Bs[16][64];
    float acc[4][4] = {};
    const int ar = tid >> 2;
    const int ak = (tid & 3) * 4;
    const int bk = tid >> 4;
    const int bn = (tid & 15) * 4;
    for (int kk = 0; kk < K; kk += 16) {
        float4 av = *(const float4*)&A[(size_t)(m0 + ar) * K + kk + ak];
        float4 bv = *(const float4*)&B[(size_t)(kk + bk) * N + n0 + bn];
        As[ak + 0][ar] = av.x; As[ak + 1][ar] = av.y;
        As[ak + 2][ar] = av.z; As[ak + 3][ar] = av.w;
        *(float4*)&Bs[bk][bn] = bv;
        __syncthreads();
#pragma unroll
        for (int k = 0; k < 16; ++k) {
            float4 a = *(const float4*)&As[k][ty * 4];
            float4 b = *(const float4*)&Bs[k][tx * 4];
            float a4[4] = {a.x, a.y, a.z, a.w};
            float b4[4] = {b.x, b.y, b.z, b.w};
#pragma unroll
            for (int i = 0; i < 4; ++i)
#pragma unroll
                for (int j = 0; j < 4; ++j) acc[i][j] += a4[i] * b4[j];
        }
        __syncthreads();
    }
#pragma unroll
    for (int i = 0; i < 4; ++i) {
        float4 o = make_float4(acc[i][0], acc[i][1], acc[i][2], acc[i][3]);
        *(float4*)&C[(size_t)(m0 + ty * 4 + i) * N + n0 + tx * 4] = o;
    }
}

// ---------------- depthwise causal conv (D_CONV=4) + bias + SiLU ----------------
__global__ void k_conv_silu(const float* __restrict__ xz, const float* __restrict__ cw,
                            const float* __restrict__ cb, float* __restrict__ u) {
    int idx = blockIdx.x * blockDim.x + threadIdx.x;
    int c  = idx & (DINNER - 1);
    int bl = idx >> 9;
    int l  = bl & (LL - 1);
    float acc = cb[c];
#pragma unroll
    for (int k = 0; k < DCONV; ++k) {
        int t = l - (DCONV - 1) + k;
        if (t >= 0) acc += cw[c * DCONV + k] * xz[(size_t)(bl - (DCONV - 1) + k) * 2 * DINNER + c];
    }
    u[(size_t)idx] = acc * sigmoidf_(acc);
}

// ---------------- fused x_proj (48 cols) + delta = softplus(dt@Wdt + b) ----------------
__global__ __launch_bounds__(256) void k_xproj_delta(const float* __restrict__ u,
                                                     const float* __restrict__ w_xp,
                                                     const float* __restrict__ w_dt,
                                                     const float* __restrict__ b_dt,
                                                     float* __restrict__ Bm,
                                                     float* __restrict__ Cm,
                                                     float* __restrict__ delta) {
    int bl = blockIdx.x;
    __shared__ float us[DINNER];
    __shared__ float dts[DTRANK];
    int tid = threadIdx.x;
    *(float2*)&us[tid * 2] = *(const float2*)&u[(size_t)bl * DINNER + tid * 2];
    __syncthreads();
    if (tid < 48) {
        float s = 0.f;
#pragma unroll 8
        for (int k = 0; k < DINNER; ++k) s += us[k] * w_xp[k * 48 + tid];
        if (tid < 16)      dts[tid] = s;
        else if (tid < 32) Bm[(size_t)bl * DSTATE + tid - 16] = s;
        else               Cm[(size_t)bl * DSTATE + tid - 32] = s;
    }
    __syncthreads();
#pragma unroll
    for (int cc = 0; cc < 2; ++cc) {
        int c = tid + cc * 256;
        float s = b_dt[c];
#pragma unroll
        for (int r = 0; r < DTRANK; ++r) s += dts[r] * w_dt[r * DINNER + c];
        delta[(size_t)bl * DINNER + c] = (s > 20.f) ? s : log1pf(__expf(s));
    }
}

// ---------------- chunked selective scan ----------------
// block = 256 = 16 channels x 16 n-lanes.
// grid block id = ((b*32 + cb)*NCHUNK + k); each block does chunk k for 16 channels.

// Pass A: scan chunk from h=0, record aprod = prod(dA) and hend.
__global__ __launch_bounds__(256) void k_scan_a(const float* __restrict__ delta,
                                                const float* __restrict__ u,
                                                const float* __restrict__ Bm,
                                                const float* __restrict__ A_log,
                                                float* __restrict__ aprod,
                                                float* __restrict__ hend) {
    int tid = threadIdx.x;
    int n  = tid & 15;
    int cg = tid >> 4;
    int blk = blockIdx.x;
    int k  = blk & (NCHUNK - 1);
    int cb = (blk >> 4) & 31;
    int b  = blk >> 9;
    int c  = cb * 16 + cg;
    const float Ac = -__expf(A_log[c * DSTATE + n]);
    const int bl0 = b * LL + k * LC;
    float h = 0.f, ap = 1.f;
#pragma unroll 2
    for (int t = 0; t < LC; ++t) {
        int bl = bl0 + t;
        float dlt = delta[(size_t)bl * DINNER + c];
        float uu  = u[(size_t)bl * DINNER + c];
        float Bn  = Bm[(size_t)bl * DSTATE + n];
        float dA  = __expf(dlt * Ac);
        h  = dA * h + (dlt * uu) * Bn;
        ap *= dA;
    }
    int idx = ((k * BB + b) * DINNER + c) * DSTATE + n;
    aprod[idx] = ap;
    hend[idx]  = h;
}

// Pass B: serial combine across chunks (one thread per (b,c,n) recurrence).
__global__ __launch_bounds__(256) void k_scan_b(const float* __restrict__ aprod,
                                                const float* __restrict__ hend,
                                                float* __restrict__ hstart) {
    int i = blockIdx.x * 256 + threadIdx.x;  // 0..NREC-1
    float h = 0.f;
#pragma unroll
    for (int k = 0; k < NCHUNK; ++k) {
        int idx = k * NREC + i;
        hstart[idx] = h;
        h = aprod[idx] * h + hend[idx];
    }
}

// Pass C: re-scan chunk from hstart, emit gated output.
__global__ __launch_bounds__(256) void k_scan_c(const float* __restrict__ delta,
                                                const float* __restrict__ u,
                                                const float* __restrict__ xz,
                                                const float* __restrict__ Bm,
                                                const float* __restrict__ Cm,
                                                const float* __restrict__ A_log,
                                                const float* __restrict__ Dp,
                                                const float* __restrict__ hstart,
                                                float* __restrict__ y) {
    int tid = threadIdx.x;
    int n  = tid & 15;
    int cg = tid >> 4;
    int blk = blockIdx.x;
    int k  = blk & (NCHUNK - 1);
    int cb = (blk >> 4) & 31;
    int b  = blk >> 9;
    int c  = cb * 16 + cg;
    const float Ac = -__expf(A_log[c * DSTATE + n]);
    const float Dc = Dp[c];
    const int bl0 = b * LL + k * LC;
    float h = hstart[((k * BB + b) * DINNER + c) * DSTATE + n];
#pragma unroll 2
    for (int t = 0; t < LC; ++t) {
        int bl = bl0 + t;
        float dlt = delta[(size_t)bl * DINNER + c];
        float uu  = u[(size_t)bl * DINNER + c];
        float Bn  = Bm[(size_t)bl * DSTATE + n];
        float Cn  = Cm[(size_t)bl * DSTATE + n];
        float dA  = __expf(dlt * Ac);
        h = dA * h + (dlt * uu) * Bn;
        float p = h * Cn;
        p += __shfl_xor(p, 1, 16);
        p += __shfl_xor(p, 2, 16);
        p += __shfl_xor(p, 4, 16);
        p += __shfl_xor(p, 8, 16);
        if (n == 0) {
            float rr = xz[(size_t)bl * 2 * DINNER + DINNER + c];
            float yv = p + uu * Dc;
            y[(size_t)bl * DINNER + c] = yv * (rr * sigmoidf_(rr));
        }
    }
}

extern "C" void kernel_launch(void* const* d_in, const int* in_sizes, int n_in,
                              void* d_out, int out_size, void* d_ws, size_t ws_size,
                              hipStream_t stream) {
    const int*   ids   = (const int*)d_in[0];
    const float* emb   = (const float*)d_in[1];
    const float* w_in  = (const float*)d_in[2];
    const float* cw    = (const float*)d_in[3];
    const float* cb    = (const float*)d_in[4];
    const float* w_xp  = (const float*)d_in[5];
    const float* w_dt  = (const float*)d_in[6];
    const float* b_dt  = (const float*)d_in[7];
    const float* A_log = (const float*)d_in[8];
    const float* Dp    = (const float*)d_in[9];
    const float* w_out = (const float*)d_in[10];
    float* out = (float*)d_out;

    float* ws = (float*)d_ws;
    float* x   = ws;                              // BL*256  (2.10M floats)
    float* xz  = x  + (size_t)BL * DMODEL;        // BL*1024
    float* u   = xz + (size_t)BL * 2 * DINNER;    // BL*512
    float* Bm  = u  + (size_t)BL * DINNER;        // BL*16
    float* Cm  = Bm + (size_t)BL * DSTATE;        // BL*16
    float* dlt = Cm + (size_t)BL * DSTATE;        // BL*512
    float* y   = dlt + (size_t)BL * DINNER;       // BL*512
    // scan scratch overlays x (dead between in_proj and out_proj):
    // 3 * NCHUNK*NREC = 1.57M floats <= 2.10M
    float* aprod  = x;
    float* hend   = aprod + (size_t)NCHUNK * NREC;
    float* hstart = hend  + (size_t)NCHUNK * NREC;

    k_embed<<<BL, DMODEL, 0, stream>>>(ids, emb, x);

    for (int l = 0; l < NLAYER; ++l) {
        dim3 g1(2 * DINNER / 64, BL / 64);
        k_sgemm<<<g1, 256, 0, stream>>>(x, w_in + (size_t)l * DMODEL * 2 * DINNER, xz,
                                        BL, 2 * DINNER, DMODEL);
        k_conv_silu<<<(BL * DINNER) / 256, 256, 0, stream>>>(
            xz, cw + l * DINNER * DCONV, cb + l * DINNER, u);
        k_xproj_delta<<<BL, 256, 0, stream>>>(u, w_xp + (size_t)l * DINNER * 48,
                                              w_dt + (size_t)l * DTRANK * DINNER,
                                              b_dt + (size_t)l * DINNER, Bm, Cm, dlt);
        const float* Al = A_log + (size_t)l * DINNER * DSTATE;
        k_scan_a<<<BB * 32 * NCHUNK, 256, 0, stream>>>(dlt, u, Bm, Al, aprod, hend);
        k_scan_b<<<NREC / 256, 256, 0, stream>>>(aprod, hend, hstart);
        k_scan_c<<<BB * 32 * NCHUNK, 256, 0, stream>>>(dlt, u, xz, Bm, Cm, Al,
                                                       Dp + (size_t)l * DINNER, hstart, y);
        float* dst = (l == NLAYER - 1) ? out : x;
        dim3 g2(DMODEL / 64, BL / 64);
        k_sgemm<<<g2, 256, 0, stream>>>(y, w_out + (size_t)l * DINNER * DMODEL, dst,
                                        BL, DMODEL, DINNER);
    }
}

// Round 3
// 491.628 us; speedup vs baseline: 3.5989x; 1.2913x over previous
//
#include <hip/hip_runtime.h>
#include <math.h>

#define NLAYER 2
#define DMODEL 256
#define DINNER 512
#define DSTATE 16
#define DTRANK 16
#define DCONV  4
#define BB     4
#define LL     2048
#define BL     (BB*LL)
#define NCHUNK 64
#define LC     (LL/NCHUNK)          // 32
#define NREC   (BB*DINNER*DSTATE)   // 32768

__device__ __forceinline__ float sigmoidf_(float x) { return 1.0f / (1.0f + __expf(-x)); }

// ---------------- embedding gather ----------------
__global__ void k_embed(const int* __restrict__ ids, const float* __restrict__ emb,
                        float* __restrict__ x) {
    int bl = blockIdx.x;
    int d  = threadIdx.x;
    int id = ids[bl];
    x[(size_t)bl * DMODEL + d] = emb[(size_t)id * DMODEL + d];
}

// ---------------- fp32 tiled GEMM: C[M,N] = A[M,K] @ B[K,N] ----------------
__global__ __launch_bounds__(256) void k_sgemm(const float* __restrict__ A,
                                               const float* __restrict__ B,
                                               float* __restrict__ C,
                                               int M, int N, int K) {
    const int tid = threadIdx.x;
    const int tx = tid & 15, ty = tid >> 4;
    const int m0 = blockIdx.y * 64, n0 = blockIdx.x * 64;
    __shared__ float As[16][64];
    __shared__ float Bs[16][64];
    float acc[4][4] = {};
    const int ar = tid >> 2;
    const int ak = (tid & 3) * 4;
    const int bk = tid >> 4;
    const int bn = (tid & 15) * 4;
    for (int kk = 0; kk < K; kk += 16) {
        float4 av = *(const float4*)&A[(size_t)(m0 + ar) * K + kk + ak];
        float4 bv = *(const float4*)&B[(size_t)(kk + bk) * N + n0 + bn];
        As[ak + 0][ar] = av.x; As[ak + 1][ar] = av.y;
        As[ak + 2][ar] = av.z; As[ak + 3][ar] = av.w;
        *(float4*)&Bs[bk][bn] = bv;
        __syncthreads();
#pragma unroll
        for (int k = 0; k < 16; ++k) {
            float4 a = *(const float4*)&As[k][ty * 4];
            float4 b = *(const float4*)&Bs[k][tx * 4];
            float a4[4] = {a.x, a.y, a.z, a.w};
            float b4[4] = {b.x, b.y, b.z, b.w};
#pragma unroll
            for (int i = 0; i < 4; ++i)
#pragma unroll
                for (int j = 0; j < 4; ++j) acc[i][j] += a4[i] * b4[j];
        }
        __syncthreads();
    }
#pragma unroll
    for (int i = 0; i < 4; ++i) {
        float4 o = make_float4(acc[i][0], acc[i][1], acc[i][2], acc[i][3]);
        *(float4*)&C[(size_t)(m0 + ty * 4 + i) * N + n0 + tx * 4] = o;
    }
}

// ---------------- depthwise causal conv (D_CONV=4) + bias + SiLU ----------------
__global__ void k_conv_silu(const float* __restrict__ xz, const float* __restrict__ cw,
                            const float* __restrict__ cb, float* __restrict__ u) {
    int idx = blockIdx.x * blockDim.x + threadIdx.x;
    int c  = idx & (DINNER - 1);
    int bl = idx >> 9;
    int l  = bl & (LL - 1);
    float acc = cb[c];
#pragma unroll
    for (int k = 0; k < DCONV; ++k) {
        int t = l - (DCONV - 1) + k;
        if (t >= 0) acc += cw[c * DCONV + k] * xz[(size_t)(bl - (DCONV - 1) + k) * 2 * DINNER + c];
    }
    u[(size_t)idx] = acc * sigmoidf_(acc);
}

// ---------------- fused x_proj (48 cols) + delta = softplus(dt@Wdt + b) ----------------
__global__ __launch_bounds__(256) void k_xproj_delta(const float* __restrict__ u,
                                                     const float* __restrict__ w_xp,
                                                     const float* __restrict__ w_dt,
                                                     const float* __restrict__ b_dt,
                                                     float* __restrict__ Bm,
                                                     float* __restrict__ Cm,
                                                     float* __restrict__ delta) {
    int bl = blockIdx.x;
    __shared__ float us[DINNER];
    __shared__ float dts[DTRANK];
    int tid = threadIdx.x;
    *(float2*)&us[tid * 2] = *(const float2*)&u[(size_t)bl * DINNER + tid * 2];
    __syncthreads();
    if (tid < 48) {
        float s = 0.f;
#pragma unroll 8
        for (int k = 0; k < DINNER; ++k) s += us[k] * w_xp[k * 48 + tid];
        if (tid < 16)      dts[tid] = s;
        else if (tid < 32) Bm[(size_t)bl * DSTATE + tid - 16] = s;
        else               Cm[(size_t)bl * DSTATE + tid - 32] = s;
    }
    __syncthreads();
#pragma unroll
    for (int cc = 0; cc < 2; ++cc) {
        int c = tid + cc * 256;
        float s = b_dt[c];
#pragma unroll
        for (int r = 0; r < DTRANK; ++r) s += dts[r] * w_dt[r * DINNER + c];
        delta[(size_t)bl * DINNER + c] = (s > 20.f) ? s : log1pf(__expf(s));
    }
}

// ---------------- chunked selective scan, per-channel 16-state-in-registers ----------------
// block = 256 threads; each thread owns one channel (16 states in VGPRs).
// grid: bid = (b<<7) | (k<<1) | chalf ; chalf selects channels [0..255] or [256..511].

// Pass A: scan chunk from h=0, record aprod = prod(dA), hend per (k,b,c,n).
__global__ __launch_bounds__(256) void k_scan_a(const float* __restrict__ delta,
                                                const float* __restrict__ u,
                                                const float* __restrict__ Bm,
                                                const float* __restrict__ A_log,
                                                float* __restrict__ aprod,
                                                float* __restrict__ hend) {
    const int tid = threadIdx.x;
    const int bid = blockIdx.x;
    const int chalf = bid & 1;
    const int k = (bid >> 1) & (NCHUNK - 1);
    const int b = bid >> 7;
    const int c = chalf * 256 + tid;
    const int bl0 = b * LL + k * LC;

    __shared__ float Bs[LC * DSTATE];
    for (int i = tid; i < LC * DSTATE; i += 256) Bs[i] = Bm[(size_t)bl0 * DSTATE + i];
    __syncthreads();

    float Ac[DSTATE];
#pragma unroll
    for (int q = 0; q < 4; ++q) {
        float4 a = *(const float4*)&A_log[c * DSTATE + q * 4];
        Ac[q * 4 + 0] = -__expf(a.x); Ac[q * 4 + 1] = -__expf(a.y);
        Ac[q * 4 + 2] = -__expf(a.z); Ac[q * 4 + 3] = -__expf(a.w);
    }

    float h[DSTATE] = {};
    float ap[DSTATE];
#pragma unroll
    for (int n = 0; n < DSTATE; ++n) ap[n] = 1.f;

    float dlt = delta[(size_t)bl0 * DINNER + c];
    float uu  = u[(size_t)bl0 * DINNER + c];
    for (int t = 0; t < LC; ++t) {
        float dlt2 = 0.f, uu2 = 0.f;
        if (t + 1 < LC) {
            dlt2 = delta[(size_t)(bl0 + t + 1) * DINNER + c];
            uu2  = u[(size_t)(bl0 + t + 1) * DINNER + c];
        }
        const float w = dlt * uu;
        const float4* Bs4 = (const float4*)&Bs[t * DSTATE];
        float4 b0 = Bs4[0], b1 = Bs4[1], b2 = Bs4[2], b3 = Bs4[3];
        float bv[DSTATE] = {b0.x, b0.y, b0.z, b0.w, b1.x, b1.y, b1.z, b1.w,
                            b2.x, b2.y, b2.z, b2.w, b3.x, b3.y, b3.z, b3.w};
#pragma unroll
        for (int n = 0; n < DSTATE; ++n) {
            float dA = __expf(dlt * Ac[n]);
            ap[n] *= dA;
            h[n] = fmaf(dA, h[n], w * bv[n]);
        }
        dlt = dlt2; uu = uu2;
    }
    size_t base = ((size_t)(k * BB + b) * DINNER + c) * DSTATE;
#pragma unroll
    for (int q = 0; q < 4; ++q) {
        *(float4*)&aprod[base + q * 4] = make_float4(ap[q*4], ap[q*4+1], ap[q*4+2], ap[q*4+3]);
        *(float4*)&hend[base + q * 4]  = make_float4(h[q*4],  h[q*4+1],  h[q*4+2],  h[q*4+3]);
    }
}

// Pass B: serial combine across chunks (one thread per (b,c,n)).
// NOTE: hstart may alias aprod (read-before-write order below).
__global__ __launch_bounds__(256) void k_scan_b(const float* __restrict__ aprod,
                                                const float* __restrict__ hend,
                                                float* __restrict__ hstart) {
    int i = blockIdx.x * 256 + threadIdx.x;
    float h = 0.f;
#pragma unroll 4
    for (int k = 0; k < NCHUNK; ++k) {
        size_t idx = (size_t)k * NREC + i;
        float a = aprod[idx];
        float e = hend[idx];
        hstart[idx] = h;
        h = fmaf(a, h, e);
    }
}

// Pass C: re-scan chunk from hstart, emit gated output.
__global__ __launch_bounds__(256) void k_scan_c(const float* __restrict__ delta,
                                                const float* __restrict__ u,
                                                const float* __restrict__ xz,
                                                const float* __restrict__ Bm,
                                                const float* __restrict__ Cm,
                                                const float* __restrict__ A_log,
                                                const float* __restrict__ Dp,
                                                const float* __restrict__ hstart,
                                                float* __restrict__ y) {
    const int tid = threadIdx.x;
    const int bid = blockIdx.x;
    const int chalf = bid & 1;
    const int k = (bid >> 1) & (NCHUNK - 1);
    const int b = bid >> 7;
    const int c = chalf * 256 + tid;
    const int bl0 = b * LL + k * LC;

    __shared__ float Bs[LC * DSTATE];
    __shared__ float Cs[LC * DSTATE];
    for (int i = tid; i < LC * DSTATE; i += 256) {
        Bs[i] = Bm[(size_t)bl0 * DSTATE + i];
        Cs[i] = Cm[(size_t)bl0 * DSTATE + i];
    }
    __syncthreads();

    float Ac[DSTATE];
#pragma unroll
    for (int q = 0; q < 4; ++q) {
        float4 a = *(const float4*)&A_log[c * DSTATE + q * 4];
        Ac[q * 4 + 0] = -__expf(a.x); Ac[q * 4 + 1] = -__expf(a.y);
        Ac[q * 4 + 2] = -__expf(a.z); Ac[q * 4 + 3] = -__expf(a.w);
    }
    const float Dc = Dp[c];

    float h[DSTATE];
    size_t hbase = ((size_t)(k * BB + b) * DINNER + c) * DSTATE;
#pragma unroll
    for (int q = 0; q < 4; ++q) {
        float4 hv = *(const float4*)&hstart[hbase + q * 4];
        h[q*4] = hv.x; h[q*4+1] = hv.y; h[q*4+2] = hv.z; h[q*4+3] = hv.w;
    }

    float dlt = delta[(size_t)bl0 * DINNER + c];
    float uu  = u[(size_t)bl0 * DINNER + c];
    float rr  = xz[(size_t)bl0 * 2 * DINNER + DINNER + c];
    for (int t = 0; t < LC; ++t) {
        float dlt2 = 0.f, uu2 = 0.f, rr2 = 0.f;
        if (t + 1 < LC) {
            dlt2 = delta[(size_t)(bl0 + t + 1) * DINNER + c];
            uu2  = u[(size_t)(bl0 + t + 1) * DINNER + c];
            rr2  = xz[(size_t)(bl0 + t + 1) * 2 * DINNER + DINNER + c];
        }
        const float w = dlt * uu;
        const float4* Bs4 = (const float4*)&Bs[t * DSTATE];
        float4 b0 = Bs4[0], b1 = Bs4[1], b2 = Bs4[2], b3 = Bs4[3];
        float bv[DSTATE] = {b0.x, b0.y, b0.z, b0.w, b1.x, b1.y, b1.z, b1.w,
                            b2.x, b2.y, b2.z, b2.w, b3.x, b3.y, b3.z, b3.w};
        const float4* Cs4 = (const float4*)&Cs[t * DSTATE];
        float4 c0 = Cs4[0], c1 = Cs4[1], c2 = Cs4[2], c3 = Cs4[3];
        float cv[DSTATE] = {c0.x, c0.y, c0.z, c0.w, c1.x, c1.y, c1.z, c1.w,
                            c2.x, c2.y, c2.z, c2.w, c3.x, c3.y, c3.z, c3.w};
        float s0 = 0.f, s1 = 0.f, s2 = 0.f, s3 = 0.f;
#pragma unroll
        for (int n = 0; n < DSTATE; n += 4) {
            float dA0 = __expf(dlt * Ac[n+0]);
            float dA1 = __expf(dlt * Ac[n+1]);
            float dA2 = __expf(dlt * Ac[n+2]);
            float dA3 = __expf(dlt * Ac[n+3]);
            h[n+0] = fmaf(dA0, h[n+0], w * bv[n+0]);
            h[n+1] = fmaf(dA1, h[n+1], w * bv[n+1]);
            h[n+2] = fmaf(dA2, h[n+2], w * bv[n+2]);
            h[n+3] = fmaf(dA3, h[n+3], w * bv[n+3]);
            s0 = fmaf(h[n+0], cv[n+0], s0);
            s1 = fmaf(h[n+1], cv[n+1], s1);
            s2 = fmaf(h[n+2], cv[n+2], s2);
            s3 = fmaf(h[n+3], cv[n+3], s3);
        }
        float yv = (s0 + s1) + (s2 + s3) + uu * Dc;
        y[(size_t)(bl0 + t) * DINNER + c] = yv * (rr * sigmoidf_(rr));
        dlt = dlt2; uu = uu2; rr = rr2;
    }
}

extern "C" void kernel_launch(void* const* d_in, const int* in_sizes, int n_in,
                              void* d_out, int out_size, void* d_ws, size_t ws_size,
                              hipStream_t stream) {
    const int*   ids   = (const int*)d_in[0];
    const float* emb   = (const float*)d_in[1];
    const float* w_in  = (const float*)d_in[2];
    const float* cw    = (const float*)d_in[3];
    const float* cb    = (const float*)d_in[4];
    const float* w_xp  = (const float*)d_in[5];
    const float* w_dt  = (const float*)d_in[6];
    const float* b_dt  = (const float*)d_in[7];
    const float* A_log = (const float*)d_in[8];
    const float* Dp    = (const float*)d_in[9];
    const float* w_out = (const float*)d_in[10];
    float* out = (float*)d_out;

    float* ws = (float*)d_ws;
    float* x   = ws;                              // BL*256 = 2.097M floats
    float* xz  = x  + (size_t)BL * DMODEL;        // BL*1024
    float* u   = xz + (size_t)BL * 2 * DINNER;    // BL*512
    float* Bm  = u  + (size_t)BL * DINNER;        // BL*16
    float* Cm  = Bm + (size_t)BL * DSTATE;        // BL*16
    float* dlt = Cm + (size_t)BL * DSTATE;        // BL*512
    float* y   = dlt + (size_t)BL * DINNER;       // BL*512
    float* hend = y + (size_t)BL * DINNER;        // NCHUNK*NREC = 2.097M
    // aprod overlays x (dead during scan); hstart aliases aprod (scan_b is
    // read-before-write per element).  NCHUNK*NREC == BL*DMODEL exactly.
    float* aprod  = x;
    float* hstart = aprod;

    k_embed<<<BL, DMODEL, 0, stream>>>(ids, emb, x);

    for (int l = 0; l < NLAYER; ++l) {
        dim3 g1(2 * DINNER / 64, BL / 64);
        k_sgemm<<<g1, 256, 0, stream>>>(x, w_in + (size_t)l * DMODEL * 2 * DINNER, xz,
                                        BL, 2 * DINNER, DMODEL);
        k_conv_silu<<<(BL * DINNER) / 256, 256, 0, stream>>>(
            xz, cw + l * DINNER * DCONV, cb + l * DINNER, u);
        k_xproj_delta<<<BL, 256, 0, stream>>>(u, w_xp + (size_t)l * DINNER * 48,
                                              w_dt + (size_t)l * DTRANK * DINNER,
                                              b_dt + (size_t)l * DINNER, Bm, Cm, dlt);
        const float* Al = A_log + (size_t)l * DINNER * DSTATE;
        k_scan_a<<<BB * NCHUNK * 2, 256, 0, stream>>>(dlt, u, Bm, Al, aprod, hend);
        k_scan_b<<<NREC / 256, 256, 0, stream>>>(aprod, hend, hstart);
        k_scan_c<<<BB * NCHUNK * 2, 256, 0, stream>>>(dlt, u, xz, Bm, Cm, Al,
                                                      Dp + (size_t)l * DINNER, hstart, y);
        float* dst = (l == NLAYER - 1) ? out : x;
        dim3 g2(DMODEL / 64, BL / 64);
        k_sgemm<<<g2, 256, 0, stream>>>(y, w_out + (size_t)l * DINNER * DMODEL, dst,
                                        BL, DMODEL, DINNER);
    }
}